// Round 4
// baseline (192.454 us; speedup 1.0000x reference)
//
#include <hip/hip_runtime.h>
#include <hip/hip_bf16.h>

#define EMBED 768
#define HID 768
#define DTOT 1536
#define NASP 32
#define BATCHN 256
#define CH 16        // samples per chunk (>= typical max n_a -> ~no duplication)
#define MAXCHUNK 48  // 32 + 256/16
#define NTILE 6      // 768 / 128 column tiles
#define DSPLIT 8     // 1536 / 192 row splits
#define DROWS (DTOT / DSPLIT)   // 192 rows per block

// ws layout (bytes):
//   [0)      int tilecnt[MAXCHUNK*NTILE]   -- zeroed each call
//   [2048)   int chcnt[MAXCHUNK]           -- zeroed each call
//   [4096)   float plog[BATCHN][NTILE][2]  -- fully overwritten before read
//   [20480)  float part[DSPLIT][BATCHN][HID]

__global__ __launch_bounds__(256, 4) void fused_kernel(
    const float* __restrict__ vX, const float* __restrict__ vH,
    const float* __restrict__ W1, const int* __restrict__ aspect_ids,
    const float* __restrict__ b1, const float* __restrict__ W2,
    const float* __restrict__ b2,
    int* __restrict__ tilecnt, int* __restrict__ chcnt,
    float* __restrict__ plog, float* __restrict__ part,
    float* __restrict__ logits)
{
    __shared__ int wcnt[4][NASP];          // per-wave aspect counts
    __shared__ int basearr[NASP];          // chunk base per aspect
    __shared__ int countsarr[NASP];        // total count per aspect
    __shared__ int chasp[MAXCHUNK];        // chunk -> aspect
    __shared__ int smpall[MAXCHUNK][CH];   // chunk -> sample ids
    __shared__ int nchunks_s;
    __shared__ __align__(16) float Vs[DROWS][CH];  // 12 KB transposed V
    __shared__ __align__(16) float4 red[512];      // 8 KB reduce buffer
    __shared__ int amfin, amlast;

    int t = threadIdx.x;
    int lane = t & 63;
    int wave = t >> 6;
    int myaid = aspect_ids[t];

    // --- deterministic bucketing (identical in every block) ---
    unsigned long long mymask = 0ull;
    for (int a = 0; a < NASP; ++a) {
        bool p = (myaid == a);
        unsigned long long m = __ballot(p);
        if (p) mymask = m;
        if (lane == a) wcnt[wave][a] = __popcll(m);
    }
    __syncthreads();
    if (t < NASP) {
        int ctot = wcnt[0][t] + wcnt[1][t] + wcnt[2][t] + wcnt[3][t];
        countsarr[t] = ctot;
        int nc = (ctot + CH - 1) / CH;
        int incl = nc;
        #pragma unroll
        for (int off = 1; off < NASP; off <<= 1) {
            int v = __shfl_up(incl, off, 64);
            if (t >= off) incl += v;
        }
        int base = incl - nc;
        basearr[t] = base;
        for (int j = 0; j < nc; ++j) chasp[base + j] = t;
        if (t == NASP - 1) nchunks_s = incl;
    }
    __syncthreads();
    {
        int pre = 0;
        for (int w2i = 0; w2i < wave; ++w2i) pre += wcnt[w2i][myaid];
        int r = pre + __popcll(mymask & ((1ull << lane) - 1ull));
        int c = basearr[myaid] + r / CH;
        smpall[c][r % CH] = t;
    }
    __syncthreads();

    int bid = blockIdx.x;
    int chunk = bid / (NTILE * DSPLIT);
    if (chunk >= nchunks_s) return;
    int rem  = bid % (NTILE * DSPLIT);
    int tile = rem / DSPLIT;
    int dsp  = rem % DSPLIT;

    int aspect = chasp[chunk];
    int cnt = countsarr[aspect] - CH * (chunk - basearr[aspect]);
    if (cnt > CH) cnt = CH;

    int dbase = dsp * DROWS;

    // --- stage V transposed: Vs[d][s] ---
    #pragma unroll
    for (int r = 0; r < 3; ++r) {
        int id = t + r * 256;   // 768 = 48 row-quads * 16 samples
        int s = id & (CH - 1);
        int f = id >> 4;
        int smp = (s < cnt) ? smpall[chunk][s] : smpall[chunk][0];
        int d = dbase + f * 4;
        const float* src = (dbase < EMBED)
            ? (vX + (size_t)smp * EMBED + d)
            : (vH + (size_t)smp * HID + (d - EMBED));
        float4 v = *(const float4*)src;
        Vs[f * 4 + 0][s] = v.x;
        Vs[f * 4 + 1][s] = v.y;
        Vs[f * 4 + 2][s] = v.z;
        Vs[f * 4 + 3][s] = v.w;
    }
    __syncthreads();

    int c32 = t & 31;
    int dg  = t >> 5;
    int h0  = tile * 128 + c32 * 4;

    const float* wp = W1 + (size_t)aspect * ((size_t)DTOT * HID)
                         + (size_t)(dbase + dg) * HID + h0;

    float4 acc[CH];
    #pragma unroll
    for (int s = 0; s < CH; ++s) { acc[s].x = acc[s].y = acc[s].z = acc[s].w = 0.f; }

    #pragma unroll 4
    for (int k = 0; k < DROWS / 8; ++k) {   // 24 iterations
        float4 w = *(const float4*)wp;
        wp += 8 * HID;
        int d = k * 8 + dg;
        float4 va = *(const float4*)&Vs[d][0];
        float4 vb = *(const float4*)&Vs[d][4];
        float4 vc = *(const float4*)&Vs[d][8];
        float4 vd = *(const float4*)&Vs[d][12];
        acc[0].x  += va.x * w.x; acc[0].y  += va.x * w.y; acc[0].z  += va.x * w.z; acc[0].w  += va.x * w.w;
        acc[1].x  += va.y * w.x; acc[1].y  += va.y * w.y; acc[1].z  += va.y * w.z; acc[1].w  += va.y * w.w;
        acc[2].x  += va.z * w.x; acc[2].y  += va.z * w.y; acc[2].z  += va.z * w.z; acc[2].w  += va.z * w.w;
        acc[3].x  += va.w * w.x; acc[3].y  += va.w * w.y; acc[3].z  += va.w * w.z; acc[3].w  += va.w * w.w;
        acc[4].x  += vb.x * w.x; acc[4].y  += vb.x * w.y; acc[4].z  += vb.x * w.z; acc[4].w  += vb.x * w.w;
        acc[5].x  += vb.y * w.x; acc[5].y  += vb.y * w.y; acc[5].z  += vb.y * w.z; acc[5].w  += vb.y * w.w;
        acc[6].x  += vb.z * w.x; acc[6].y  += vb.z * w.y; acc[6].z  += vb.z * w.z; acc[6].w  += vb.z * w.w;
        acc[7].x  += vb.w * w.x; acc[7].y  += vb.w * w.y; acc[7].z  += vb.w * w.z; acc[7].w  += vb.w * w.w;
        acc[8].x  += vc.x * w.x; acc[8].y  += vc.x * w.y; acc[8].z  += vc.x * w.z; acc[8].w  += vc.x * w.w;
        acc[9].x  += vc.y * w.x; acc[9].y  += vc.y * w.y; acc[9].z  += vc.y * w.z; acc[9].w  += vc.y * w.w;
        acc[10].x += vc.z * w.x; acc[10].y += vc.z * w.y; acc[10].z += vc.z * w.z; acc[10].w += vc.z * w.w;
        acc[11].x += vc.w * w.x; acc[11].y += vc.w * w.y; acc[11].z += vc.w * w.z; acc[11].w += vc.w * w.w;
        acc[12].x += vd.x * w.x; acc[12].y += vd.x * w.y; acc[12].z += vd.x * w.z; acc[12].w += vd.x * w.w;
        acc[13].x += vd.y * w.x; acc[13].y += vd.y * w.y; acc[13].z += vd.y * w.z; acc[13].w += vd.y * w.w;
        acc[14].x += vd.z * w.x; acc[14].y += vd.z * w.y; acc[14].z += vd.z * w.z; acc[14].w += vd.z * w.w;
        acc[15].x += vd.w * w.x; acc[15].y += vd.w * w.y; acc[15].z += vd.w * w.z; acc[15].w += vd.w * w.w;
    }

    // --- reduce over dg via LDS, 2 samples per round; write part ---
    size_t dsp_off = (size_t)dsp * BATCHN * HID;
    #pragma unroll
    for (int sp = 0; sp < CH / 2; ++sp) {
        __syncthreads();
        red[t]       = acc[2 * sp + 0];
        red[256 + t] = acc[2 * sp + 1];
        __syncthreads();
        if (t < 64) {
            int half = t >> 5;
            int l32  = t & 31;
            int s = 2 * sp + half;
            float4 sum = red[half * 256 + l32];
            #pragma unroll
            for (int g = 1; g < 8; ++g) {
                float4 o = red[half * 256 + g * 32 + l32];
                sum.x += o.x; sum.y += o.y; sum.z += o.z; sum.w += o.w;
            }
            if (s < cnt) {
                int smp = smpall[chunk][s];
                *(float4*)&part[dsp_off + (size_t)smp * HID + tile * 128 + l32 * 4] = sum;
            }
        }
    }

    // --- finisher election for this (chunk, tile) ---
    __syncthreads();
    if (t == 0) {
        __threadfence();
        int old = atomicAdd(&tilecnt[chunk * NTILE + tile], 1);
        amfin = (old == DSPLIT - 1);
    }
    __syncthreads();
    if (!amfin) return;
    __threadfence();   // acquire: other blocks' part writes

    // finisher: sum 8 partials, bias+ReLU, dot with W2 slice -> plog
    {
        int s = t >> 4;        // 0..15 sample
        int j = t & 15;        // col-octet within the 128-col tile
        float p0 = 0.f, p1 = 0.f;
        if (s < cnt) {
            int smp = smpall[chunk][s];
            const float* b1p = b1 + (size_t)aspect * HID;
            const float* w2  = W2 + (size_t)aspect * HID * 2;
            int hbase = tile * 128 + j * 8;
            #pragma unroll
            for (int c = 0; c < 8; ++c) {
                int h = hbase + c;
                float o = 0.f;
                #pragma unroll
                for (int p = 0; p < DSPLIT; ++p)
                    o += part[((size_t)p * BATCHN + smp) * HID + h];
                o = fmaxf(o + b1p[h], 0.f);
                p0 += o * w2[h * 2 + 0];
                p1 += o * w2[h * 2 + 1];
            }
        }
        #pragma unroll
        for (int off = 8; off > 0; off >>= 1) {   // reduce over j (16 lanes, same s contiguous)
            p0 += __shfl_down(p0, off, 64);
            p1 += __shfl_down(p1, off, 64);
        }
        if (j == 0 && s < cnt) {
            int smp = smpall[chunk][s];
            plog[((size_t)smp * NTILE + tile) * 2 + 0] = p0;
            plog[((size_t)smp * NTILE + tile) * 2 + 1] = p1;
        }
    }

    // --- combiner election for this chunk (6th tile finisher) ---
    __syncthreads();
    if (t == 0) {
        __threadfence();
        int old2 = atomicAdd(&chcnt[chunk], 1);
        amlast = (old2 == NTILE - 1);
    }
    __syncthreads();
    if (!amlast) return;
    __threadfence();

    if (t < 2 * CH) {
        int s2 = t >> 1, k = t & 1;
        if (s2 < cnt) {
            int smp = smpall[chunk][s2];
            float v = b2[aspect * 2 + k];
            #pragma unroll
            for (int tl = 0; tl < NTILE; ++tl)
                v += plog[((size_t)smp * NTILE + tl) * 2 + k];
            logits[smp * 2 + k] = v;
        }
    }
}

extern "C" void kernel_launch(void* const* d_in, const int* in_sizes, int n_in,
                              void* d_out, int out_size, void* d_ws, size_t ws_size,
                              hipStream_t stream) {
    const float* vX  = (const float*)d_in[0];
    const float* vH  = (const float*)d_in[1];
    const int*   aid = (const int*)d_in[2];
    const float* W1  = (const float*)d_in[3];
    const float* b1  = (const float*)d_in[4];
    const float* W2  = (const float*)d_in[5];
    const float* b2  = (const float*)d_in[6];
    float* logits = (float*)d_out;

    int*   tilecnt = (int*)d_ws;
    int*   chcnt   = (int*)((char*)d_ws + 2048);
    float* plog    = (float*)((char*)d_ws + 4096);
    float* part    = (float*)((char*)d_ws + 20480);

    hipMemsetAsync(d_ws, 0, 4096, stream);   // zero tilecnt + chcnt

    fused_kernel<<<MAXCHUNK * NTILE * DSPLIT, 256, 0, stream>>>(
        vX, vH, W1, aid, b1, W2, b2, tilecnt, chcnt, plog, part, logits);
}

// Round 5
// 48.582 us; speedup vs baseline: 3.9615x; 3.9615x over previous
//
#include <hip/hip_runtime.h>
#include <hip/hip_bf16.h>

#define EMBED 768
#define HID 768
#define DTOT 1536
#define NASP 32
#define BATCHN 256
#define CH 16        // samples per chunk
#define MAXCHUNK 48  // sum ceil(n_a/16) <= 47
#define COLS 32      // columns per tile (one 128B L2 line)
#define NT2 (HID / COLS)      // 24 tiles
#define SROWS 192             // rows staged per phase
#define NSTAGE (DTOT / SROWS) // 8 phases
#define VSP 20       // padded LDS row stride (floats): conflict-free b128 reads

// ws layout: float plog[NT2][BATCHN][2]  (49 KB) -- every slot written each call

__global__ __launch_bounds__(256, 4) void gemv_fused_kernel(
    const float* __restrict__ vX, const float* __restrict__ vH,
    const float* __restrict__ W1, const int* __restrict__ aspect_ids,
    const float* __restrict__ b1, const float* __restrict__ W2,
    float* __restrict__ plog)
{
    __shared__ int wcnt[4][NASP];
    __shared__ int basearr[NASP];
    __shared__ int countsarr[NASP];
    __shared__ int chasp[MAXCHUNK];
    __shared__ int smpall[MAXCHUNK][CH];
    __shared__ int nchunks_s;
    __shared__ __align__(16) float Vs[SROWS * VSP];      // 15.4 KB padded V tile
    __shared__ __align__(16) float4 redw[8][4][8];       // 4 KB  [j][wave][c]

    int t = threadIdx.x;
    int lane = t & 63;
    int wave = t >> 6;
    int myaid = aspect_ids[t];

    // --- deterministic bucketing (identical in every block) ---
    unsigned long long mymask = 0ull;
    for (int a = 0; a < NASP; ++a) {
        bool p = (myaid == a);
        unsigned long long m = __ballot(p);
        if (p) mymask = m;
        if (lane == a) wcnt[wave][a] = __popcll(m);
    }
    __syncthreads();
    if (t < NASP) {
        int ctot = wcnt[0][t] + wcnt[1][t] + wcnt[2][t] + wcnt[3][t];
        countsarr[t] = ctot;
        int nc = (ctot + CH - 1) / CH;
        int incl = nc;
        #pragma unroll
        for (int off = 1; off < NASP; off <<= 1) {
            int v = __shfl_up(incl, off, 64);
            if (t >= off) incl += v;
        }
        int base = incl - nc;
        basearr[t] = base;
        for (int j = 0; j < nc; ++j) chasp[base + j] = t;
        if (t == NASP - 1) nchunks_s = incl;
    }
    __syncthreads();
    {
        int pre = 0;
        for (int w = 0; w < wave; ++w) pre += wcnt[w][myaid];
        int r = pre + __popcll(mymask & ((1ull << lane) - 1ull));
        int c = basearr[myaid] + r / CH;
        smpall[c][r % CH] = t;
    }
    __syncthreads();

    int bid = blockIdx.x;
    int chunk = bid / NT2;
    if (chunk >= nchunks_s) return;
    int tile = bid % NT2;

    int aspect = chasp[chunk];
    int cnt = countsarr[aspect] - CH * (chunk - basearr[aspect]);
    if (cnt > CH) cnt = CH;

    int c8 = t & 7;       // float4-column 0..7 within the 32-col tile
    int dg = t >> 3;      // row offset 0..31

    const float* wp = W1 + (size_t)aspect * ((size_t)DTOT * HID)
                         + (size_t)dg * HID + tile * COLS + c8 * 4;

    float4 acc[CH];
    #pragma unroll
    for (int s = 0; s < CH; ++s) { acc[s].x = acc[s].y = acc[s].z = acc[s].w = 0.f; }

    for (int st = 0; st < NSTAGE; ++st) {
        int dbase = st * SROWS;
        __syncthreads();   // protect Vs from previous phase's readers
        // stage V transposed+padded: Vs[row*VSP + s]
        #pragma unroll
        for (int r = 0; r < 3; ++r) {
            int id = t + r * 256;          // 768 = 48 row-quads * 16 samples
            int s = id & (CH - 1);
            int f = id >> 4;
            int smp = (s < cnt) ? smpall[chunk][s] : smpall[chunk][0];
            int d = dbase + f * 4;
            const float* src = (dbase < EMBED)
                ? (vX + (size_t)smp * EMBED + d)
                : (vH + (size_t)smp * HID + (d - EMBED));
            float4 v = *(const float4*)src;
            Vs[(f * 4 + 0) * VSP + s] = v.x;
            Vs[(f * 4 + 1) * VSP + s] = v.y;
            Vs[(f * 4 + 2) * VSP + s] = v.z;
            Vs[(f * 4 + 3) * VSP + s] = v.w;
        }
        __syncthreads();

        #pragma unroll
        for (int kk = 0; kk < SROWS / 32; ++kk) {   // 6 iterations
            float4 w = *(const float4*)wp;
            wp += 32 * HID;
            const float* vrow = &Vs[(kk * 32 + dg) * VSP];
            float4 va = *(const float4*)(vrow + 0);
            float4 vb = *(const float4*)(vrow + 4);
            float4 vc = *(const float4*)(vrow + 8);
            float4 vd = *(const float4*)(vrow + 12);
            acc[0].x  += va.x * w.x; acc[0].y  += va.x * w.y; acc[0].z  += va.x * w.z; acc[0].w  += va.x * w.w;
            acc[1].x  += va.y * w.x; acc[1].y  += va.y * w.y; acc[1].z  += va.y * w.z; acc[1].w  += va.y * w.w;
            acc[2].x  += va.z * w.x; acc[2].y  += va.z * w.y; acc[2].z  += va.z * w.z; acc[2].w  += va.z * w.w;
            acc[3].x  += va.w * w.x; acc[3].y  += va.w * w.y; acc[3].z  += va.w * w.z; acc[3].w  += va.w * w.w;
            acc[4].x  += vb.x * w.x; acc[4].y  += vb.x * w.y; acc[4].z  += vb.x * w.z; acc[4].w  += vb.x * w.w;
            acc[5].x  += vb.y * w.x; acc[5].y  += vb.y * w.y; acc[5].z  += vb.y * w.z; acc[5].w  += vb.y * w.w;
            acc[6].x  += vb.z * w.x; acc[6].y  += vb.z * w.y; acc[6].z  += vb.z * w.z; acc[6].w  += vb.z * w.w;
            acc[7].x  += vb.w * w.x; acc[7].y  += vb.w * w.y; acc[7].z  += vb.w * w.z; acc[7].w  += vb.w * w.w;
            acc[8].x  += vc.x * w.x; acc[8].y  += vc.x * w.y; acc[8].z  += vc.x * w.z; acc[8].w  += vc.x * w.w;
            acc[9].x  += vc.y * w.x; acc[9].y  += vc.y * w.y; acc[9].z  += vc.y * w.z; acc[9].w  += vc.y * w.w;
            acc[10].x += vc.z * w.x; acc[10].y += vc.z * w.y; acc[10].z += vc.z * w.z; acc[10].w += vc.z * w.w;
            acc[11].x += vc.w * w.x; acc[11].y += vc.w * w.y; acc[11].z += vc.w * w.z; acc[11].w += vc.w * w.w;
            acc[12].x += vd.x * w.x; acc[12].y += vd.x * w.y; acc[12].z += vd.x * w.z; acc[12].w += vd.x * w.w;
            acc[13].x += vd.y * w.x; acc[13].y += vd.y * w.y; acc[13].z += vd.y * w.z; acc[13].w += vd.y * w.w;
            acc[14].x += vd.z * w.x; acc[14].y += vd.z * w.y; acc[14].z += vd.z * w.z; acc[14].w += vd.z * w.w;
            acc[15].x += vd.w * w.x; acc[15].y += vd.w * w.y; acc[15].z += vd.w * w.z; acc[15].w += vd.w * w.w;
        }
    }

    // --- in-wave reduce over the 8 dg-groups of each wave (lanes 0..7 hold sums) ---
    #pragma unroll
    for (int s = 0; s < CH; ++s) {
        float4 v = acc[s];
        v.x += __shfl_down(v.x, 32, 64); v.y += __shfl_down(v.y, 32, 64);
        v.z += __shfl_down(v.z, 32, 64); v.w += __shfl_down(v.w, 32, 64);
        v.x += __shfl_down(v.x, 16, 64); v.y += __shfl_down(v.y, 16, 64);
        v.z += __shfl_down(v.z, 16, 64); v.w += __shfl_down(v.w, 16, 64);
        v.x += __shfl_down(v.x,  8, 64); v.y += __shfl_down(v.y,  8, 64);
        v.z += __shfl_down(v.z,  8, 64); v.w += __shfl_down(v.w,  8, 64);
        acc[s] = v;
    }

    // --- cross-wave reduce + fused epilogue, 8 samples per round ---
    const float* b1p = b1 + (size_t)aspect * HID;
    const float* w2p = W2 + (size_t)aspect * HID * 2;
    #pragma unroll
    for (int rr = 0; rr < 2; ++rr) {
        __syncthreads();
        if (lane < 8) {
            #pragma unroll
            for (int j = 0; j < 8; ++j)
                redw[j][wave][lane] = acc[rr * 8 + j];
        }
        __syncthreads();
        // all 64 lanes of wave 0: j = t>>3 (sample-in-round), c = t&7 (col quad)
        if (wave == 0) {
            int j = t >> 3;
            int c = t & 7;
            int s = rr * 8 + j;
            float4 a0 = redw[j][0][c], a1 = redw[j][1][c];
            float4 a2 = redw[j][2][c], a3 = redw[j][3][c];
            float4 sum;
            sum.x = a0.x + a1.x + a2.x + a3.x;
            sum.y = a0.y + a1.y + a2.y + a3.y;
            sum.z = a0.z + a1.z + a2.z + a3.z;
            sum.w = a0.w + a1.w + a2.w + a3.w;
            int h = tile * COLS + c * 4;
            float p0 = 0.f, p1 = 0.f;
            if (s < cnt) {
                float o;
                o = fmaxf(sum.x + b1p[h + 0], 0.f); p0 += o * w2p[(h + 0) * 2]; p1 += o * w2p[(h + 0) * 2 + 1];
                o = fmaxf(sum.y + b1p[h + 1], 0.f); p0 += o * w2p[(h + 1) * 2]; p1 += o * w2p[(h + 1) * 2 + 1];
                o = fmaxf(sum.z + b1p[h + 2], 0.f); p0 += o * w2p[(h + 2) * 2]; p1 += o * w2p[(h + 2) * 2 + 1];
                o = fmaxf(sum.w + b1p[h + 3], 0.f); p0 += o * w2p[(h + 3) * 2]; p1 += o * w2p[(h + 3) * 2 + 1];
            }
            p0 += __shfl_down(p0, 4, 64); p1 += __shfl_down(p1, 4, 64);
            p0 += __shfl_down(p0, 2, 64); p1 += __shfl_down(p1, 2, 64);
            p0 += __shfl_down(p0, 1, 64); p1 += __shfl_down(p1, 1, 64);
            if (c == 0 && s < cnt) {
                int smp = smpall[chunk][s];
                float2 pv; pv.x = p0; pv.y = p1;
                *(float2*)&plog[((size_t)tile * BATCHN + smp) * 2] = pv;
            }
        }
    }
}

__global__ __launch_bounds__(BATCHN) void combine_kernel(
    const float* __restrict__ plog, const int* __restrict__ aspect_ids,
    const float* __restrict__ b2, float* __restrict__ logits)
{
    int smp = threadIdx.x;
    int a = aspect_ids[smp];
    float p0 = b2[a * 2 + 0], p1 = b2[a * 2 + 1];
    const float2* pl = (const float2*)plog;
    #pragma unroll
    for (int tl = 0; tl < NT2; ++tl) {
        float2 v = pl[(size_t)tl * BATCHN + smp];
        p0 += v.x; p1 += v.y;
    }
    float2 out; out.x = p0; out.y = p1;
    *(float2*)&logits[smp * 2] = out;
}

extern "C" void kernel_launch(void* const* d_in, const int* in_sizes, int n_in,
                              void* d_out, int out_size, void* d_ws, size_t ws_size,
                              hipStream_t stream) {
    const float* vX  = (const float*)d_in[0];
    const float* vH  = (const float*)d_in[1];
    const int*   aid = (const int*)d_in[2];
    const float* W1  = (const float*)d_in[3];
    const float* b1  = (const float*)d_in[4];
    const float* W2  = (const float*)d_in[5];
    const float* b2  = (const float*)d_in[6];
    float* logits = (float*)d_out;

    float* plog = (float*)d_ws;   // 24*256*2*4 = 49 KB, fully rewritten each call

    gemv_fused_kernel<<<MAXCHUNK * NT2, 256, 0, stream>>>(
        vX, vH, W1, aid, b1, W2, plog);
    combine_kernel<<<1, BATCHN, 0, stream>>>(plog, aid, b2, logits);
}

// Round 6
// 43.882 us; speedup vs baseline: 4.3858x; 1.1071x over previous
//
#include <hip/hip_runtime.h>
#include <hip/hip_bf16.h>

#define EMBED 768
#define HID 768
#define DTOT 1536
#define NASP 32
#define BATCHN 256
#define CH 16        // samples per chunk
#define MAXCHUNK 48  // sum ceil(n_a/16) <= 48
#define COLS 128     // columns per tile -> 512B contiguous per W row segment
#define NT (HID / COLS)       // 6 tiles
#define SROWS 192             // rows staged per phase
#define NSTAGE (DTOT / SROWS) // 8 phases
#define DG 16                 // row-depth (threads = 32 cols * DG)
#define VSP 20       // padded LDS V row stride (floats); 16B-aligned, 2-way max on store

// ws layout: float plog[NT][BATCHN][2] (12 KB) -- every slot written each call

__global__ __launch_bounds__(512, 2) void gemv_fused_kernel(
    const float* __restrict__ vX, const float* __restrict__ vH,
    const float* __restrict__ W1, const int* __restrict__ aspect_ids,
    const float* __restrict__ b1, const float* __restrict__ W2,
    float* __restrict__ plog)
{
    __shared__ int wcnt[4][NASP];
    __shared__ int basearr[NASP];
    __shared__ int countsarr[NASP];
    __shared__ int chasp[MAXCHUNK];
    __shared__ int smpall[MAXCHUNK][CH];
    __shared__ int nchunks_s;
    __shared__ __align__(16) float Vs[SROWS * VSP];   // 15.4 KB padded V tile
    __shared__ __align__(16) float4 red[4][8][32];    // 16 KB [sample-in-round][wave][col]

    int t = threadIdx.x;
    int lane = t & 63;
    int wave = t >> 6;

    // --- deterministic bucketing (waves 0-3 only; identical in every block) ---
    if (t < BATCHN) {
        int myaid = aspect_ids[t];
        unsigned long long mymask = 0ull;
        for (int a = 0; a < NASP; ++a) {
            bool p = (myaid == a);
            unsigned long long m = __ballot(p);
            if (p) mymask = m;
            if (lane == a) wcnt[wave][a] = __popcll(m);
        }
        __syncthreads();
        if (t < NASP) {
            int ctot = wcnt[0][t] + wcnt[1][t] + wcnt[2][t] + wcnt[3][t];
            countsarr[t] = ctot;
            int nc = (ctot + CH - 1) / CH;
            int incl = nc;
            #pragma unroll
            for (int off = 1; off < NASP; off <<= 1) {
                int v = __shfl_up(incl, off, 64);
                if (t >= off) incl += v;
            }
            int base = incl - nc;
            basearr[t] = base;
            for (int j = 0; j < nc; ++j) chasp[base + j] = t;
            if (t == NASP - 1) nchunks_s = incl;
        }
        __syncthreads();
        {
            int pre = 0;
            for (int w = 0; w < wave; ++w) pre += wcnt[w][myaid];
            int r = pre + __popcll(mymask & ((1ull << lane) - 1ull));
            int c = basearr[myaid] + r / CH;
            smpall[c][r % CH] = t;
        }
    } else {
        __syncthreads();
        __syncthreads();
    }
    __syncthreads();

    int bid = blockIdx.x;
    int chunk = bid / NT;
    if (chunk >= nchunks_s) return;
    int tile = bid % NT;

    int aspect = chasp[chunk];
    int cnt = countsarr[aspect] - CH * (chunk - basearr[aspect]);
    if (cnt > CH) cnt = CH;

    int c32 = t & 31;     // float4-col within the 128-col tile
    int dg  = t >> 5;     // row offset 0..15

    const float* wp = W1 + (size_t)aspect * ((size_t)DTOT * HID)
                         + (size_t)dg * HID + tile * COLS + c32 * 4;

    float4 acc[CH];
    #pragma unroll
    for (int s = 0; s < CH; ++s) { acc[s].x = acc[s].y = acc[s].z = acc[s].w = 0.f; }

    for (int st = 0; st < NSTAGE; ++st) {
        int dbase = st * SROWS;
        __syncthreads();   // protect Vs from previous phase's readers
        // stage V transposed+padded: Vs[row*VSP + s]; 768 float4 loads, 512 threads
        {
            int id = t;                      // 0..511
            int s = id & (CH - 1);
            int f = id >> 4;                 // 0..31
            int smp = (s < cnt) ? smpall[chunk][s] : smpall[chunk][0];
            int d = dbase + f * 4;
            const float* src = (dbase < EMBED)
                ? (vX + (size_t)smp * EMBED + d)
                : (vH + (size_t)smp * HID + (d - EMBED));
            float4 v = *(const float4*)src;
            Vs[(f * 4 + 0) * VSP + s] = v.x;
            Vs[(f * 4 + 1) * VSP + s] = v.y;
            Vs[(f * 4 + 2) * VSP + s] = v.z;
            Vs[(f * 4 + 3) * VSP + s] = v.w;
        }
        if (t < 256) {
            int id = t + 512;
            int s = id & (CH - 1);
            int f = id >> 4;                 // 32..47
            int smp = (s < cnt) ? smpall[chunk][s] : smpall[chunk][0];
            int d = dbase + f * 4;
            const float* src = (dbase < EMBED)
                ? (vX + (size_t)smp * EMBED + d)
                : (vH + (size_t)smp * HID + (d - EMBED));
            float4 v = *(const float4*)src;
            Vs[(f * 4 + 0) * VSP + s] = v.x;
            Vs[(f * 4 + 1) * VSP + s] = v.y;
            Vs[(f * 4 + 2) * VSP + s] = v.z;
            Vs[(f * 4 + 3) * VSP + s] = v.w;
        }
        __syncthreads();

        #pragma unroll
        for (int k = 0; k < SROWS / DG; ++k) {   // 12 iterations, fully unrolled
            float4 w = *(const float4*)wp;
            wp += DG * HID;
            const float* vrow = &Vs[(k * DG + dg) * VSP];
            float4 va = *(const float4*)(vrow + 0);
            float4 vb = *(const float4*)(vrow + 4);
            float4 vc = *(const float4*)(vrow + 8);
            float4 vd = *(const float4*)(vrow + 12);
            acc[0].x  += va.x * w.x; acc[0].y  += va.x * w.y; acc[0].z  += va.x * w.z; acc[0].w  += va.x * w.w;
            acc[1].x  += va.y * w.x; acc[1].y  += va.y * w.y; acc[1].z  += va.y * w.z; acc[1].w  += va.y * w.w;
            acc[2].x  += va.z * w.x; acc[2].y  += va.z * w.y; acc[2].z  += va.z * w.z; acc[2].w  += va.z * w.w;
            acc[3].x  += va.w * w.x; acc[3].y  += va.w * w.y; acc[3].z  += va.w * w.z; acc[3].w  += va.w * w.w;
            acc[4].x  += vb.x * w.x; acc[4].y  += vb.x * w.y; acc[4].z  += vb.x * w.z; acc[4].w  += vb.x * w.w;
            acc[5].x  += vb.y * w.x; acc[5].y  += vb.y * w.y; acc[5].z  += vb.y * w.z; acc[5].w  += vb.y * w.w;
            acc[6].x  += vb.z * w.x; acc[6].y  += vb.z * w.y; acc[6].z  += vb.z * w.z; acc[6].w  += vb.z * w.w;
            acc[7].x  += vb.w * w.x; acc[7].y  += vb.w * w.y; acc[7].z  += vb.w * w.z; acc[7].w  += vb.w * w.w;
            acc[8].x  += vc.x * w.x; acc[8].y  += vc.x * w.y; acc[8].z  += vc.x * w.z; acc[8].w  += vc.x * w.w;
            acc[9].x  += vc.y * w.x; acc[9].y  += vc.y * w.y; acc[9].z  += vc.y * w.z; acc[9].w  += vc.y * w.w;
            acc[10].x += vc.z * w.x; acc[10].y += vc.z * w.y; acc[10].z += vc.z * w.z; acc[10].w += vc.z * w.w;
            acc[11].x += vc.w * w.x; acc[11].y += vc.w * w.y; acc[11].z += vc.w * w.z; acc[11].w += vc.w * w.w;
            acc[12].x += vd.x * w.x; acc[12].y += vd.x * w.y; acc[12].z += vd.x * w.z; acc[12].w += vd.x * w.w;
            acc[13].x += vd.y * w.x; acc[13].y += vd.y * w.y; acc[13].z += vd.y * w.z; acc[13].w += vd.y * w.w;
            acc[14].x += vd.z * w.x; acc[14].y += vd.z * w.y; acc[14].z += vd.z * w.z; acc[14].w += vd.z * w.w;
            acc[15].x += vd.w * w.x; acc[15].y += vd.w * w.y; acc[15].z += vd.w * w.z; acc[15].w += vd.w * w.w;
        }
    }

    // --- fold dg pairs in-wave: lanes 0..31 hold sum of dg={2w,2w+1} ---
    #pragma unroll
    for (int s = 0; s < CH; ++s) {
        float4 v = acc[s];
        v.x += __shfl_down(v.x, 32, 64); v.y += __shfl_down(v.y, 32, 64);
        v.z += __shfl_down(v.z, 32, 64); v.w += __shfl_down(v.w, 32, 64);
        acc[s] = v;
    }

    // --- cross-wave reduce + fused epilogue, 4 samples per round ---
    const float* b1p = b1 + (size_t)aspect * HID;
    const float* w2p = W2 + (size_t)aspect * HID * 2;
    #pragma unroll
    for (int rr = 0; rr < 4; ++rr) {
        __syncthreads();
        if (lane < 32) {
            #pragma unroll
            for (int j = 0; j < 4; ++j)
                red[j][wave][lane] = acc[rr * 4 + j];
        }
        __syncthreads();
        if (t < 128) {   // waves 0-1: j = t>>5 (sample-in-round), c = t&31
            int j = t >> 5;
            int c = t & 31;
            int s = rr * 4 + j;
            float4 sum = red[j][0][c];
            #pragma unroll
            for (int g = 1; g < 8; ++g) {
                float4 o = red[j][g][c];
                sum.x += o.x; sum.y += o.y; sum.z += o.z; sum.w += o.w;
            }
            float p0 = 0.f, p1 = 0.f;
            if (s < cnt) {
                int h = tile * COLS + c * 4;
                float o;
                o = fmaxf(sum.x + b1p[h + 0], 0.f); p0 += o * w2p[(h + 0) * 2]; p1 += o * w2p[(h + 0) * 2 + 1];
                o = fmaxf(sum.y + b1p[h + 1], 0.f); p0 += o * w2p[(h + 1) * 2]; p1 += o * w2p[(h + 1) * 2 + 1];
                o = fmaxf(sum.z + b1p[h + 2], 0.f); p0 += o * w2p[(h + 2) * 2]; p1 += o * w2p[(h + 2) * 2 + 1];
                o = fmaxf(sum.w + b1p[h + 3], 0.f); p0 += o * w2p[(h + 3) * 2]; p1 += o * w2p[(h + 3) * 2 + 1];
            }
            // reduce over c within each 32-lane half
            p0 += __shfl_down(p0, 16, 32); p1 += __shfl_down(p1, 16, 32);
            p0 += __shfl_down(p0,  8, 32); p1 += __shfl_down(p1,  8, 32);
            p0 += __shfl_down(p0,  4, 32); p1 += __shfl_down(p1,  4, 32);
            p0 += __shfl_down(p0,  2, 32); p1 += __shfl_down(p1,  2, 32);
            p0 += __shfl_down(p0,  1, 32); p1 += __shfl_down(p1,  1, 32);
            if (c == 0 && s < cnt) {
                int smp = smpall[chunk][s];
                float2 pv; pv.x = p0; pv.y = p1;
                *(float2*)&plog[((size_t)tile * BATCHN + smp) * 2] = pv;
            }
        }
    }
}

__global__ __launch_bounds__(BATCHN) void combine_kernel(
    const float* __restrict__ plog, const int* __restrict__ aspect_ids,
    const float* __restrict__ b2, float* __restrict__ logits)
{
    int smp = threadIdx.x;
    int a = aspect_ids[smp];
    float p0 = b2[a * 2 + 0], p1 = b2[a * 2 + 1];
    const float2* pl = (const float2*)plog;
    #pragma unroll
    for (int tl = 0; tl < NT; ++tl) {
        float2 v = pl[(size_t)tl * BATCHN + smp];
        p0 += v.x; p1 += v.y;
    }
    float2 out; out.x = p0; out.y = p1;
    *(float2*)&logits[smp * 2] = out;
}

extern "C" void kernel_launch(void* const* d_in, const int* in_sizes, int n_in,
                              void* d_out, int out_size, void* d_ws, size_t ws_size,
                              hipStream_t stream) {
    const float* vX  = (const float*)d_in[0];
    const float* vH  = (const float*)d_in[1];
    const int*   aid = (const int*)d_in[2];
    const float* W1  = (const float*)d_in[3];
    const float* b1  = (const float*)d_in[4];
    const float* W2  = (const float*)d_in[5];
    const float* b2  = (const float*)d_in[6];
    float* logits = (float*)d_out;

    float* plog = (float*)d_ws;   // 6*256*2*4 = 12 KB, fully rewritten each call

    gemv_fused_kernel<<<MAXCHUNK * NT, 512, 0, stream>>>(
        vX, vH, W1, aid, b1, W2, plog);
    combine_kernel<<<1, BATCHN, 0, stream>>>(plog, aid, b2, logits);
}

// Round 7
// 43.833 us; speedup vs baseline: 4.3906x; 1.0011x over previous
//
#include <hip/hip_runtime.h>
#include <hip/hip_bf16.h>

#define EMBED 768
#define HID 768
#define DTOT 1536
#define NASP 32
#define BATCHN 256
#define CH 16        // samples per chunk
#define MAXCHUNK 48  // sum ceil(n_a/16) <= 48
#define NTILE 6      // 768 / 128 column tiles
#define DSPLIT 4     // 1536 / 384 row splits
#define DROWS (DTOT / DSPLIT)   // 384 rows per block
#define SROWS 192               // rows staged per phase (2 phases)

__global__ __launch_bounds__(256, 4) void gemv1_kernel(
    const float* __restrict__ vX, const float* __restrict__ vH,
    const float* __restrict__ W1, const int* __restrict__ aspect_ids,
    float* __restrict__ part)
{
    __shared__ int wcnt[4][NASP];
    __shared__ int basearr[NASP];
    __shared__ int countsarr[NASP];
    __shared__ int chasp[MAXCHUNK];
    __shared__ int smpall[MAXCHUNK][CH];
    __shared__ int nchunks_s;
    __shared__ __align__(16) float Vs[SROWS][CH];     // 12 KB transposed V tile
    __shared__ __align__(16) float4 red[4][4][32];    // 8 KB [j][wave][col]

    int t = threadIdx.x;
    int lane = t & 63;
    int wave = t >> 6;
    int myaid = aspect_ids[t];

    // --- deterministic bucketing (identical in every block) ---
    unsigned long long mymask = 0ull;
    for (int a = 0; a < NASP; ++a) {
        bool p = (myaid == a);
        unsigned long long m = __ballot(p);
        if (p) mymask = m;
        if (lane == a) wcnt[wave][a] = __popcll(m);
    }
    __syncthreads();
    if (t < NASP) {
        int ctot = wcnt[0][t] + wcnt[1][t] + wcnt[2][t] + wcnt[3][t];
        countsarr[t] = ctot;
        int nc = (ctot + CH - 1) / CH;
        int incl = nc;
        #pragma unroll
        for (int off = 1; off < NASP; off <<= 1) {
            int v = __shfl_up(incl, off, 64);
            if (t >= off) incl += v;
        }
        int base = incl - nc;
        basearr[t] = base;
        for (int j = 0; j < nc; ++j) chasp[base + j] = t;
        if (t == NASP - 1) nchunks_s = incl;
    }
    __syncthreads();
    {
        int pre = 0;
        for (int w = 0; w < wave; ++w) pre += wcnt[w][myaid];
        int r = pre + __popcll(mymask & ((1ull << lane) - 1ull));
        int c = basearr[myaid] + r / CH;
        smpall[c][r % CH] = t;
    }
    __syncthreads();

    int bid = blockIdx.x;
    int chunk = bid / (NTILE * DSPLIT);
    if (chunk >= nchunks_s) return;
    int rem  = bid % (NTILE * DSPLIT);
    int tile = rem / DSPLIT;
    int dsp  = rem % DSPLIT;

    int aspect = chasp[chunk];
    int cnt = countsarr[aspect] - CH * (chunk - basearr[aspect]);
    if (cnt > CH) cnt = CH;

    int c32 = t & 31;     // float4-col within the 128-col tile
    int dg  = t >> 5;     // row offset 0..7

    const float* wp = W1 + (size_t)aspect * ((size_t)DTOT * HID)
                         + (size_t)(dsp * DROWS + dg) * HID + tile * 128 + c32 * 4;

    float4 acc[CH];
    #pragma unroll
    for (int s = 0; s < CH; ++s) { acc[s].x = acc[s].y = acc[s].z = acc[s].w = 0.f; }

    for (int st = 0; st < DROWS / SROWS; ++st) {   // 2 phases
        int dbase = dsp * DROWS + st * SROWS;
        __syncthreads();   // protect Vs from previous phase's readers
        // stage 192 rows x 16 samples, transposed: Vs[d][s]
        #pragma unroll
        for (int r = 0; r < 3; ++r) {
            int id = t + r * 256;   // 768 = 48 row-quads * 16 samples
            int s = id & (CH - 1);
            int f = id >> 4;
            int smp = (s < cnt) ? smpall[chunk][s] : smpall[chunk][0];
            int d = dbase + f * 4;
            const float* src = (dbase < EMBED)
                ? (vX + (size_t)smp * EMBED + d)
                : (vH + (size_t)smp * HID + (d - EMBED));
            float4 v = *(const float4*)src;
            Vs[f * 4 + 0][s] = v.x;
            Vs[f * 4 + 1][s] = v.y;
            Vs[f * 4 + 2][s] = v.z;
            Vs[f * 4 + 3][s] = v.w;
        }
        __syncthreads();

        #pragma unroll 4
        for (int k = 0; k < SROWS / 8; ++k) {   // 24 iterations
            float4 w = *(const float4*)wp;
            wp += 8 * HID;
            int d = k * 8 + dg;
            float4 va = *(const float4*)&Vs[d][0];
            float4 vb = *(const float4*)&Vs[d][4];
            float4 vc = *(const float4*)&Vs[d][8];
            float4 vd = *(const float4*)&Vs[d][12];
            acc[0].x  += va.x * w.x; acc[0].y  += va.x * w.y; acc[0].z  += va.x * w.z; acc[0].w  += va.x * w.w;
            acc[1].x  += va.y * w.x; acc[1].y  += va.y * w.y; acc[1].z  += va.y * w.z; acc[1].w  += va.y * w.w;
            acc[2].x  += va.z * w.x; acc[2].y  += va.z * w.y; acc[2].z  += va.z * w.z; acc[2].w  += va.z * w.w;
            acc[3].x  += va.w * w.x; acc[3].y  += va.w * w.y; acc[3].z  += va.w * w.z; acc[3].w  += va.w * w.w;
            acc[4].x  += vb.x * w.x; acc[4].y  += vb.x * w.y; acc[4].z  += vb.x * w.z; acc[4].w  += vb.x * w.w;
            acc[5].x  += vb.y * w.x; acc[5].y  += vb.y * w.y; acc[5].z  += vb.y * w.z; acc[5].w  += vb.y * w.w;
            acc[6].x  += vb.z * w.x; acc[6].y  += vb.z * w.y; acc[6].z  += vb.z * w.z; acc[6].w  += vb.z * w.w;
            acc[7].x  += vb.w * w.x; acc[7].y  += vb.w * w.y; acc[7].z  += vb.w * w.z; acc[7].w  += vb.w * w.w;
            acc[8].x  += vc.x * w.x; acc[8].y  += vc.x * w.y; acc[8].z  += vc.x * w.z; acc[8].w  += vc.x * w.w;
            acc[9].x  += vc.y * w.x; acc[9].y  += vc.y * w.y; acc[9].z  += vc.y * w.z; acc[9].w  += vc.y * w.w;
            acc[10].x += vc.z * w.x; acc[10].y += vc.z * w.y; acc[10].z += vc.z * w.z; acc[10].w += vc.z * w.w;
            acc[11].x += vc.w * w.x; acc[11].y += vc.w * w.y; acc[11].z += vc.w * w.z; acc[11].w += vc.w * w.w;
            acc[12].x += vd.x * w.x; acc[12].y += vd.x * w.y; acc[12].z += vd.x * w.z; acc[12].w += vd.x * w.w;
            acc[13].x += vd.y * w.x; acc[13].y += vd.y * w.y; acc[13].z += vd.y * w.z; acc[13].w += vd.y * w.w;
            acc[14].x += vd.z * w.x; acc[14].y += vd.z * w.y; acc[14].z += vd.z * w.z; acc[14].w += vd.z * w.w;
            acc[15].x += vd.w * w.x; acc[15].y += vd.w * w.y; acc[15].z += vd.w * w.z; acc[15].w += vd.w * w.w;
        }
    }

    // --- fold dg pairs in-wave: lanes 0..31 of wave w hold dg={2w,2w+1} sums ---
    #pragma unroll
    for (int s = 0; s < CH; ++s) {
        float4 v = acc[s];
        v.x += __shfl_down(v.x, 32, 64); v.y += __shfl_down(v.y, 32, 64);
        v.z += __shfl_down(v.z, 32, 64); v.w += __shfl_down(v.w, 32, 64);
        acc[s] = v;
    }

    // --- cross-wave reduce, 4 samples per round; write part ---
    size_t dsp_off = (size_t)dsp * BATCHN * HID;
    #pragma unroll
    for (int rr = 0; rr < 4; ++rr) {
        __syncthreads();
        if (lane < 32) {
            #pragma unroll
            for (int j = 0; j < 4; ++j)
                red[j][wave][lane] = acc[rr * 4 + j];
        }
        __syncthreads();
        if (t < 128) {            // j = t>>5 (sample-in-round), c = t&31
            int j = t >> 5;
            int c = t & 31;
            int s = rr * 4 + j;
            float4 a0 = red[j][0][c], a1 = red[j][1][c];
            float4 a2 = red[j][2][c], a3 = red[j][3][c];
            float4 sum;
            sum.x = a0.x + a1.x + a2.x + a3.x;
            sum.y = a0.y + a1.y + a2.y + a3.y;
            sum.z = a0.z + a1.z + a2.z + a3.z;
            sum.w = a0.w + a1.w + a2.w + a3.w;
            if (s < cnt) {
                int smp = smpall[chunk][s];
                *(float4*)&part[dsp_off + (size_t)smp * HID + tile * 128 + c * 4] = sum;
            }
        }
    }
}

__global__ __launch_bounds__(64) void head_kernel(
    const float* __restrict__ part, const int* __restrict__ aspect_ids,
    const float* __restrict__ b1, const float* __restrict__ W2,
    const float* __restrict__ b2, float* __restrict__ logits)
{
    int s = blockIdx.x;
    int t = threadIdx.x;
    int a = aspect_ids[s];
    const float* w2 = W2 + (size_t)a * HID * 2;
    const float* b1p = b1 + (size_t)a * HID;
    float p0 = 0.f, p1 = 0.f;
    #pragma unroll
    for (int j = 0; j < HID / 64; ++j) {
        int hh = t + j * 64;
        float o = 0.f;
        #pragma unroll
        for (int p = 0; p < DSPLIT; ++p) {
            o += part[(size_t)p * BATCHN * HID + (size_t)s * HID + hh];
        }
        o = fmaxf(o + b1p[hh], 0.f);
        p0 += o * w2[hh * 2 + 0];
        p1 += o * w2[hh * 2 + 1];
    }
    #pragma unroll
    for (int off = 32; off > 0; off >>= 1) {
        p0 += __shfl_down(p0, off, 64);
        p1 += __shfl_down(p1, off, 64);
    }
    if (t == 0) {
        logits[s * 2 + 0] = p0 + b2[a * 2 + 0];
        logits[s * 2 + 1] = p1 + b2[a * 2 + 1];
    }
}

extern "C" void kernel_launch(void* const* d_in, const int* in_sizes, int n_in,
                              void* d_out, int out_size, void* d_ws, size_t ws_size,
                              hipStream_t stream) {
    const float* vX  = (const float*)d_in[0];
    const float* vH  = (const float*)d_in[1];
    const int*   aid = (const int*)d_in[2];
    const float* W1  = (const float*)d_in[3];
    const float* b1  = (const float*)d_in[4];
    const float* W2  = (const float*)d_in[5];
    const float* b2  = (const float*)d_in[6];
    float* logits = (float*)d_out;

    float* part = (float*)d_ws;   // 4*256*768*4 = 3.15 MB

    gemv1_kernel<<<MAXCHUNK * NTILE * DSPLIT, 256, 0, stream>>>(vX, vH, W1, aid, part);
    head_kernel<<<BATCHN, 64, 0, stream>>>(part, aid, b1, W2, b2, logits);
}